// Round 3
// baseline (69.247 us; speedup 1.0000x reference)
//
#include <hip/hip_runtime.h>
#include <math.h>

#define NXg 302
#define NYg 394
#define Bb  16
#define Dd  128
#define Kk  16
#define UNITS 96
#define Gg  (NXg * NYg)           // 118988
#define JT8 50                    // 49 full 8-groups + 1 group of 2 per row
#define THREADS_PER_B (NXg * JT8) // 15100

static constexpr float SCALE_S    = 0.84932184f;   // sqrt(0.5 * log2(e))
static constexpr float INV_SCALE  = 1.0f / 0.84932184f;
static constexpr float INV_TWO_PI = 0.15915494309f;

__device__ __forceinline__ float fast_exp2(float x) {
#if __has_builtin(__builtin_amdgcn_exp2f)
    return __builtin_amdgcn_exp2f(x);
#else
    return exp2f(x);
#endif
}

// ---------------------------------------------------------------------------
// Kernel 1: one block per batch row. 2 threads per output unit (d split in
// halves) to halve the cold-load latency chain. Params per (b,k):
//   [mu0, mu1, a/s, s/L11 | s/L22, weight/(2*pi*L11*L22), 0, 0]
// ---------------------------------------------------------------------------
__global__ __launch_bounds__(192) void mdn_setup(
    const float* __restrict__ in,     // [B][D]
    const float* __restrict__ w,      // [D][UNITS]
    const float* __restrict__ bias,   // [UNITS]
    float* __restrict__ params)       // [B][K][8]
{
    const int b = blockIdx.x;
    const int t = threadIdx.x;        // 0..191

    __shared__ float insh[Dd];
    __shared__ float partial[2][UNITS];
    __shared__ float ysh[UNITS];

    if (t < Dd) insh[t] = in[b * Dd + t];
    __syncthreads();

    {
        const int u = t >> 1;          // 0..95
        const int h = t & 1;           // d half
        const int d0 = h * 64;
        float a0 = 0.f, a1 = 0.f, a2 = 0.f, a3 = 0.f;
        #pragma unroll 8
        for (int d = 0; d < 64; d += 4) {
            a0 = fmaf(insh[d0 + d + 0], w[(d0 + d + 0) * UNITS + u], a0);
            a1 = fmaf(insh[d0 + d + 1], w[(d0 + d + 1) * UNITS + u], a1);
            a2 = fmaf(insh[d0 + d + 2], w[(d0 + d + 2) * UNITS + u], a2);
            a3 = fmaf(insh[d0 + d + 3], w[(d0 + d + 3) * UNITS + u], a3);
        }
        partial[h][u] = (a0 + a1) + (a2 + a3);
    }
    __syncthreads();

    if (t < UNITS) ysh[t] = partial[0][t] + partial[1][t] + bias[t];
    __syncthreads();

    if (t < Kk) {
        float pmax = -3.4e38f;
        #pragma unroll
        for (int k = 0; k < Kk; ++k) pmax = fmaxf(pmax, ysh[5 * Kk + k]);
        float sum = 0.f;
        #pragma unroll
        for (int k = 0; k < Kk; ++k) sum += __expf(ysh[5 * Kk + k] - pmax);

        const int k = t;
        const float wgt = __expf(ysh[5 * Kk + k] - pmax) / sum;
        const float mu0 = ysh[2 * k];
        const float mu1 = ysh[2 * k + 1];
        const float a   = ysh[2 * Kk + 3 * k + 0];
        const float l22 = __expf(ysh[2 * Kk + 3 * k + 1]);
        const float l11 = __expf(ysh[2 * Kk + 3 * k + 2]);
        const float c   = wgt * INV_TWO_PI / (l11 * l22);

        float* o = params + (b * Kk + k) * 8;
        o[0] = mu0;
        o[1] = mu1;
        o[2] = a * INV_SCALE;       // a'
        o[3] = SCALE_S / l11;       // i11
        o[4] = SCALE_S / l22;       // i22
        o[5] = c;
        o[6] = 0.f;
        o[7] = 0.f;
    }
}

// ---------------------------------------------------------------------------
// Kernel 2: each thread owns 8 consecutive j in ONE row i; per mixture k the
// x-dependent terms (z1, z1sq, uq) are computed once and amortized over 8 pts:
//   per point: z2 = fma(py, i22, -uq); m = fma(z2,z2,z1sq); acc += c*exp2(-m)
// ---------------------------------------------------------------------------
__global__ __launch_bounds__(256) void mdn_eval(
    const float4* __restrict__ params,   // [B][K][2] float4
    float* __restrict__ out)             // [B][G]
{
    const int b = blockIdx.y;
    const unsigned gid = blockIdx.x * 256u + threadIdx.x;
    if (gid >= (unsigned)THREADS_PER_B) return;

    const unsigned i  = gid / (unsigned)JT8;      // row (magic-mul)
    const unsigned jt = gid - i * (unsigned)JT8;  // 8-point group in row
    const unsigned j0 = jt * 8u;

    const float px = (float)i * (1.0f / (float)(NXg - 1));
    float py[8];
    #pragma unroll
    for (int t = 0; t < 8; ++t)
        py[t] = (float)(j0 + (unsigned)t) * (1.0f / (float)(NYg - 1));

    float acc[8] = {0.f, 0.f, 0.f, 0.f, 0.f, 0.f, 0.f, 0.f};
    const float4* pb = params + b * Kk * 2;

    #pragma unroll
    for (int k = 0; k < Kk; ++k) {
        const float4 lo = pb[2 * k];       // uniform per block -> cached
        const float4 hi = pb[2 * k + 1];
        const float z1   = (px - lo.x) * lo.w;           // (px-mu0)*i11
        const float z1sq = z1 * z1;
        const float uq   = fmaf(lo.z, z1, lo.y) * hi.x;  // (mu1+a'z1)*i22
        const float i22  = hi.x;
        const float c    = hi.y;
        #pragma unroll
        for (int t = 0; t < 8; ++t) {
            const float z2 = fmaf(py[t], i22, -uq);
            const float m  = fmaf(z2, z2, z1sq);
            acc[t] = fmaf(c, fast_exp2(-m), acc[t]);
        }
    }

    float* op = out + (size_t)b * Gg + (size_t)i * NYg + j0;
    if (jt < (unsigned)(JT8 - 1)) {
        #pragma unroll
        for (int t = 0; t < 4; ++t) {
            float2 r; r.x = acc[2 * t]; r.y = acc[2 * t + 1];
            reinterpret_cast<float2*>(op + 2 * t)[0] = r;
        }
    } else {
        float2 r; r.x = acc[0]; r.y = acc[1];   // j = 392, 393 only
        reinterpret_cast<float2*>(op)[0] = r;
    }
}

// ---------------------------------------------------------------------------
extern "C" void kernel_launch(void* const* d_in, const int* in_sizes, int n_in,
                              void* d_out, int out_size, void* d_ws, size_t ws_size,
                              hipStream_t stream) {
    const float* in   = (const float*)d_in[0];   // [16][128]
    const float* w    = (const float*)d_in[1];   // [128][96]
    const float* bias = (const float*)d_in[2];   // [96]
    float* out        = (float*)d_out;           // [16][302][394]
    float* params     = (float*)d_ws;            // [16][16][8] = 8 KiB

    mdn_setup<<<dim3(Bb, 1, 1), dim3(192, 1, 1), 0, stream>>>(in, w, bias, params);

    dim3 grid((THREADS_PER_B + 255) / 256, Bb, 1);   // (59, 16)
    mdn_eval<<<grid, dim3(256, 1, 1), 0, stream>>>(
        reinterpret_cast<const float4*>(params), out);
}